// Round 2
// baseline (127.735 us; speedup 1.0000x reference)
//
#include <hip/hip_runtime.h>
#include <hip/hip_bf16.h>

// NormalizedCutLoss via MFMA pair-tiles.
// Per pixel two packed bf16 rows (96 bf16 = 192B):
//  A-side (j): [Shi(21)|Slo(21)|Shi(21)|0] [fhi(5)|flo(5)|fhi(5)|1|1|qhi|qlo|0*13], q=-0.5*sq
//  B-side (i): [Shi(21)|Shi(21)|Slo(21)|0] [fhi(5)|fhi(5)|flo(5)|thi|tlo|1|1|0*13], t=-0.5*sq
// MFMA#1+#2 (K=0..63)  -> Gram = S_j.S_i (hi/lo compensated)
// MFMA#3   (K=64..95)  -> f_j.f_i - 0.5 sq_i - 0.5 sq_j = -0.5*d2 (compensated)
// per pair: w = exp(min(-0.5 d2, 0)); num += w*Gram; den += w*stot_i.

#define NIMG 8
#define KSEG 21
#define HO 64
#define WO 64
#define PIX 4096
#define HI 128
#define WI 128
#define ROWS 96        // bf16 elements per packed row
#define JCH 32         // j-rows staged per iteration
#define NIT (PIX / JCH)

typedef __attribute__((ext_vector_type(8))) short s8v;
typedef __attribute__((ext_vector_type(4))) float f4v;

__device__ inline void hilo(float x, __hip_bfloat16& h, __hip_bfloat16& l) {
    h = __float2bfloat16(x);
    l = __float2bfloat16(x - __bfloat162float(h));
}

__global__ __launch_bounds__(256)
void prep_kernel(const float* __restrict__ images,
                 const float* __restrict__ segs,
                 const float* __restrict__ rois,
                 __hip_bfloat16* __restrict__ AJ,
                 __hip_bfloat16* __restrict__ BI,
                 float* __restrict__ stot_g,
                 double* __restrict__ acc) {
    __shared__ __align__(16) __hip_bfloat16 rows[256 * ROWS];
    int tid = threadIdx.x;
    int p = blockIdx.x * 256 + tid;
    if (blockIdx.x == 0 && tid == 0) { acc[0] = 0.0; acc[1] = 0.0; }

    int img = p >> 12, pp = p & 4095;
    int y = pp >> 6, x = pp & 63;
    int yi = 2 * y, xi = 2 * x;

    const float* im = images + (size_t)img * 3 * HI * WI;
    float f[5];
    f[0] = im[0 * HI * WI + yi * WI + xi] * (1.0f / 15.0f);
    f[1] = im[1 * HI * WI + yi * WI + xi] * (1.0f / 15.0f);
    f[2] = im[2 * HI * WI + yi * WI + xi] * (1.0f / 15.0f);
    f[3] = (float)x * (1.0f / 40.0f);
    f[4] = (float)y * (1.0f / 40.0f);
    float roi = rois[(size_t)img * HI * WI + yi * WI + xi];
    float sq = f[0]*f[0] + f[1]*f[1] + f[2]*f[2] + f[3]*f[3] + f[4]*f[4];

    float sv[KSEG], stot = 0.0f;
    const float* sgp = segs + (size_t)img * KSEG * HI * WI + yi * WI + xi;
    #pragma unroll
    for (int k = 0; k < KSEG; ++k) {
        const float* s2 = sgp + (size_t)k * HI * WI;
        sv[k] = 0.25f * (s2[0] + s2[1] + s2[WI] + s2[WI + 1]) * roi;
        stot += sv[k];
    }
    stot_g[p] = stot;
    float q = -0.5f * sq;
    __hip_bfloat16 one = __float2bfloat16(1.0f);
    __hip_bfloat16 zero = __float2bfloat16(0.0f);
    __hip_bfloat16 qh, ql; hilo(q, qh, ql);

    __hip_bfloat16* rp = rows + tid * ROWS;

    // ---- pass A: A-side (j) rows ----
    #pragma unroll
    for (int k = 0; k < KSEG; ++k) {
        __hip_bfloat16 h, l; hilo(sv[k], h, l);
        rp[k] = h; rp[21 + k] = l; rp[42 + k] = h;
    }
    rp[63] = zero;
    #pragma unroll
    for (int c = 0; c < 5; ++c) {
        __hip_bfloat16 h, l; hilo(f[c], h, l);
        rp[64 + c] = h; rp[69 + c] = l; rp[74 + c] = h;
    }
    rp[79] = one; rp[80] = one; rp[81] = qh; rp[82] = ql;
    #pragma unroll
    for (int k = 83; k < 96; ++k) rp[k] = zero;
    __syncthreads();
    {
        const float4* rv = (const float4*)rows;
        float4* dst = (float4*)(AJ + (size_t)blockIdx.x * 256 * ROWS);
        for (int c2 = tid; c2 < 256 * ROWS / 8; c2 += 256) dst[c2] = rv[c2];
    }
    __syncthreads();

    // ---- pass B: B-side (i) rows ----
    #pragma unroll
    for (int k = 0; k < KSEG; ++k) {
        __hip_bfloat16 h, l; hilo(sv[k], h, l);
        rp[k] = h; rp[21 + k] = h; rp[42 + k] = l;
    }
    rp[63] = zero;
    #pragma unroll
    for (int c = 0; c < 5; ++c) {
        __hip_bfloat16 h, l; hilo(f[c], h, l);
        rp[64 + c] = h; rp[69 + c] = h; rp[74 + c] = l;
    }
    rp[79] = qh; rp[80] = ql; rp[81] = one; rp[82] = one;
    #pragma unroll
    for (int k = 83; k < 96; ++k) rp[k] = zero;
    __syncthreads();
    {
        const float4* rv = (const float4*)rows;
        float4* dst = (float4*)(BI + (size_t)blockIdx.x * 256 * ROWS);
        for (int c2 = tid; c2 < 256 * ROWS / 8; c2 += 256) dst[c2] = rv[c2];
    }
}

__global__ __launch_bounds__(256)
void pair_kernel(const __hip_bfloat16* __restrict__ AJ,
                 const __hip_bfloat16* __restrict__ BI,
                 const float* __restrict__ stot_g,
                 double* __restrict__ acc) {
    __shared__ __align__(16) short stage[2][JCH * ROWS];
    __shared__ float red[2][4];

    int tid = threadIdx.x;
    int lane = tid & 63, wv = tid >> 6;
    int img = blockIdx.x >> 6;           // 64 blocks per image
    int grp = blockIdx.x & 63;
    int i0 = (grp * 4 + wv) * 16;        // this wave's 16 i-pixels
    int c = lane & 15, sg = lane >> 4;

    // B-side fragments (held in registers for the whole j-loop)
    const short* bi = (const short*)BI + (size_t)(img * PIX + i0 + c) * ROWS;
    s8v b1 = *(const s8v*)(bi + sg * 8);
    s8v b2 = *(const s8v*)(bi + 32 + sg * 8);
    s8v bf = *(const s8v*)(bi + 64 + sg * 8);
    float stc = stot_g[img * PIX + i0 + c];

    const short* ajg = (const short*)AJ + (size_t)img * PIX * ROWS;

    float num = 0.0f, den = 0.0f;

    auto stage_chunk = [&](int it, int buf) {
        int t = tid;
        #pragma unroll
        for (int rep = 0; rep < 2; ++rep, t += 256) {
            if (t < JCH * 12) {
                int row = t / 12, seg = t % 12;
                int sw = seg < 8 ? (seg ^ (row & 7)) : (8 + ((seg & 3) ^ (row & 3)));
                const float4* src = (const float4*)(ajg + (size_t)(it * JCH + row) * ROWS + seg * 8);
                *(float4*)(&stage[buf][row * ROWS + sw * 8]) = *src;
            }
        }
    };

    stage_chunk(0, 0);
    for (int it = 0; it < NIT; ++it) {
        int buf = it & 1;
        __syncthreads();
        if (it + 1 < NIT) stage_chunk(it + 1, buf ^ 1);
        #pragma unroll
        for (int jt = 0; jt < 2; ++jt) {
            int r = jt * 16 + c;
            const short* rb = &stage[buf][r * ROWS];
            s8v a1 = *(const s8v*)(rb + ((sg ^ (r & 7)) * 8));
            s8v a2 = *(const s8v*)(rb + (((4 + sg) ^ (r & 7)) * 8));
            s8v af = *(const s8v*)(rb + ((8 + (sg ^ (r & 3))) * 8));
            f4v zero = {0.0f, 0.0f, 0.0f, 0.0f};
            f4v g  = __builtin_amdgcn_mfma_f32_16x16x32_bf16(a1, b1, zero, 0, 0, 0);
            g      = __builtin_amdgcn_mfma_f32_16x16x32_bf16(a2, b2, g,    0, 0, 0);
            f4v lw = __builtin_amdgcn_mfma_f32_16x16x32_bf16(af, bf, zero, 0, 0, 0);
            float sw = 0.0f;
            #pragma unroll
            for (int qd = 0; qd < 4; ++qd) {
                float t2 = fminf(lw[qd], 0.0f);   // clamp d2 >= 0
                float w  = __expf(t2);
                num = fmaf(w, g[qd], num);
                sw += w;
            }
            den = fmaf(sw, stc, den);
        }
    }

    #pragma unroll
    for (int off = 32; off; off >>= 1) {
        num += __shfl_down(num, off);
        den += __shfl_down(den, off);
    }
    if (lane == 0) { red[0][wv] = num; red[1][wv] = den; }
    __syncthreads();
    if (tid == 0) {
        float a = 0.0f, b = 0.0f;
        #pragma unroll
        for (int w2 = 0; w2 < 4; ++w2) { a += red[0][w2]; b += red[1][w2]; }
        atomicAdd(&acc[0], (double)a);
        atomicAdd(&acc[1], (double)b);
    }
}

__global__ void final_kernel(const double* __restrict__ acc, float* __restrict__ out) {
    out[0] = (float)(-(acc[0] / acc[1]) / (double)NIMG);
}

extern "C" void kernel_launch(void* const* d_in, const int* in_sizes, int n_in,
                              void* d_out, int out_size, void* d_ws, size_t ws_size,
                              hipStream_t stream) {
    const float* images = (const float*)d_in[0];
    const float* segs   = (const float*)d_in[1];
    const float* rois   = (const float*)d_in[2];
    float* out = (float*)d_out;

    double* acc = (double*)d_ws;
    __hip_bfloat16* AJ = (__hip_bfloat16*)((char*)d_ws + 256);
    __hip_bfloat16* BI = AJ + (size_t)NIMG * PIX * ROWS;
    float* stot = (float*)(BI + (size_t)NIMG * PIX * ROWS);

    prep_kernel<<<NIMG * PIX / 256, 256, 0, stream>>>(images, segs, rois, AJ, BI, stot, acc);
    pair_kernel<<<512, 256, 0, stream>>>(AJ, BI, stot, acc);
    final_kernel<<<1, 1, 0, stream>>>(acc, out);
}

// Round 4
// 79.458 us; speedup vs baseline: 1.6076x; 1.6076x over previous
//
#include <hip/hip_runtime.h>
#include <hip/hip_bf16.h>

// NormalizedCutLoss via MFMA pair-tiles, v3.
// Per pixel two packed bf16 rows (96 bf16 = 192B):
//  A-side (j): [Shi(21)|Slo(21)|Shi(21)|0] [gh(5)|gl(5)|gh(5)|1|1|ph|pl|0*13]
//      where g = log2e*f_j, p = log2e*q_j, q=-0.5*sq   (A-side carries the log2e scale)
//  B-side (i): [Shi(21)|Shi(21)|Slo(21)|0] [fh(5)|fh(5)|fl(5)|th|tl|1|1|0*13]
//      where f unscaled, t = log2e*q_i
// MFMA#1+#2 (K=0..63)  -> Gram = S_j.S_i (hi/lo compensated)
// MFMA#3   (K=64..95)  -> log2e*(f_j.f_i -0.5 sq_i -0.5 sq_j) = log2e*(-0.5 d2)
// per pair: w = exp2(min(lw,0)); num += w*Gram; wsum_r += w; den = sum_r stot_r*wsum_r.

#define NIMG 8
#define KSEG 21
#define PIX 4096
#define HI 128
#define WI 128
#define ROWS 96        // bf16 per packed row (global)
#define LROW 104       // padded LDS row stride (shorts) = 208B -> conflict-free b128
#define JCH 32         // j-rows per staged chunk
#define RSUB 4         // i-subtiles (of 16) per wave -> 64 i/wave
#define IPB 256        // i per block (4 waves * 64)
#define JSPLIT 16
#define JRANGE (PIX / JSPLIT)   // 256
#define NIT (JRANGE / JCH)      // 8

typedef __attribute__((ext_vector_type(8))) short s8v;
typedef __attribute__((ext_vector_type(4))) float f4v;

#define LOG2E 1.4426950408889634f

__device__ inline void hilo(float x, __hip_bfloat16& h, __hip_bfloat16& l) {
    h = __float2bfloat16(x);
    l = __float2bfloat16(x - __bfloat162float(h));
}

__device__ inline float fast_exp2(float x) {
#if __has_builtin(__builtin_amdgcn_exp2f)
    return __builtin_amdgcn_exp2f(x);
#else
    return exp2f(x);
#endif
}

__global__ __launch_bounds__(64)
void prep_kernel(const float* __restrict__ images,
                 const float* __restrict__ segs,
                 const float* __restrict__ rois,
                 __hip_bfloat16* __restrict__ AJ,
                 __hip_bfloat16* __restrict__ BI,
                 float* __restrict__ stot_g,
                 double* __restrict__ acc) {
    __shared__ __align__(16) __hip_bfloat16 rows[64 * ROWS];
    int tid = threadIdx.x;
    int p = blockIdx.x * 64 + tid;
    if (blockIdx.x == 0 && tid == 0) { acc[0] = 0.0; acc[1] = 0.0; }

    int img = p >> 12, pp = p & 4095;
    int y = pp >> 6, x = pp & 63;
    int yi = 2 * y, xi = 2 * x;

    const float* im = images + (size_t)img * 3 * HI * WI;
    float f[5];
    f[0] = im[0 * HI * WI + yi * WI + xi] * (1.0f / 15.0f);
    f[1] = im[1 * HI * WI + yi * WI + xi] * (1.0f / 15.0f);
    f[2] = im[2 * HI * WI + yi * WI + xi] * (1.0f / 15.0f);
    f[3] = (float)x * (1.0f / 40.0f);
    f[4] = (float)y * (1.0f / 40.0f);
    float roi = rois[(size_t)img * HI * WI + yi * WI + xi];
    float sq = f[0]*f[0] + f[1]*f[1] + f[2]*f[2] + f[3]*f[3] + f[4]*f[4];

    float sv[KSEG], stot = 0.0f;
    const float* sgp = segs + (size_t)img * KSEG * HI * WI + yi * WI + xi;
    #pragma unroll
    for (int k = 0; k < KSEG; ++k) {
        const float* s2 = sgp + (size_t)k * HI * WI;
        sv[k] = 0.25f * (s2[0] + s2[1] + s2[WI] + s2[WI + 1]) * roi;
        stot += sv[k];
    }
    stot_g[p] = stot;
    float q = -0.5f * sq * LOG2E;           // pre-scaled by log2e
    __hip_bfloat16 one = __float2bfloat16(1.0f);
    __hip_bfloat16 zero = __float2bfloat16(0.0f);
    __hip_bfloat16 qh, ql; hilo(q, qh, ql);

    __hip_bfloat16* rp = rows + tid * ROWS;

    // ---- pass A: A-side (j) rows: f-block scaled by log2e ----
    #pragma unroll
    for (int k = 0; k < KSEG; ++k) {
        __hip_bfloat16 h, l; hilo(sv[k], h, l);
        rp[k] = h; rp[21 + k] = l; rp[42 + k] = h;
    }
    rp[63] = zero;
    #pragma unroll
    for (int c = 0; c < 5; ++c) {
        __hip_bfloat16 h, l; hilo(f[c] * LOG2E, h, l);
        rp[64 + c] = h; rp[69 + c] = l; rp[74 + c] = h;
    }
    rp[79] = one; rp[80] = one; rp[81] = qh; rp[82] = ql;
    #pragma unroll
    for (int k = 83; k < 96; ++k) rp[k] = zero;
    __syncthreads();
    {
        const float4* rv = (const float4*)rows;
        float4* dst = (float4*)(AJ + (size_t)blockIdx.x * 64 * ROWS);
        #pragma unroll
        for (int r = 0; r < 12; ++r) dst[tid + 64 * r] = rv[tid + 64 * r];
    }
    __syncthreads();

    // ---- pass B: B-side (i) rows: f unscaled, q scaled ----
    #pragma unroll
    for (int k = 0; k < KSEG; ++k) {
        __hip_bfloat16 h, l; hilo(sv[k], h, l);
        rp[k] = h; rp[21 + k] = h; rp[42 + k] = l;
    }
    rp[63] = zero;
    #pragma unroll
    for (int c = 0; c < 5; ++c) {
        __hip_bfloat16 h, l; hilo(f[c], h, l);
        rp[64 + c] = h; rp[69 + c] = h; rp[74 + c] = l;
    }
    rp[79] = qh; rp[80] = ql; rp[81] = one; rp[82] = one;
    #pragma unroll
    for (int k = 83; k < 96; ++k) rp[k] = zero;
    __syncthreads();
    {
        const float4* rv = (const float4*)rows;
        float4* dst = (float4*)(BI + (size_t)blockIdx.x * 64 * ROWS);
        #pragma unroll
        for (int r = 0; r < 12; ++r) dst[tid + 64 * r] = rv[tid + 64 * r];
    }
}

__global__ __launch_bounds__(256, 4)
void pair_kernel(const __hip_bfloat16* __restrict__ AJ,
                 const __hip_bfloat16* __restrict__ BI,
                 const float* __restrict__ stot_g,
                 double* __restrict__ acc) {
    __shared__ __align__(16) short stage[2][JCH * LROW];   // 2 * 6656B
    __shared__ float red[2][4];

    int tid = threadIdx.x;
    int lane = tid & 63, wv = tid >> 6;
    int b = blockIdx.x;
    int img = b >> 8;            // 256 blocks per image
    int rem = b & 255;
    int ig  = rem >> 4;          // i-group (16 per image)
    int jsp = rem & 15;          // j-split (16)
    int c = lane & 15, sg = lane >> 4;
    int i0 = ig * IPB + wv * (RSUB * 16);

    // B-side fragments: RSUB subtiles of 16 i-pixels, held for whole j-loop.
    s8v b1[RSUB], b2[RSUB], bf[RSUB];
    float stc[RSUB];
    #pragma unroll
    for (int r = 0; r < RSUB; ++r) {
        const short* bi = (const short*)BI + (size_t)(img * PIX + i0 + r * 16 + c) * ROWS;
        b1[r] = *(const s8v*)(bi + sg * 8);
        b2[r] = *(const s8v*)(bi + 32 + sg * 8);
        bf[r] = *(const s8v*)(bi + 64 + sg * 8);
        stc[r] = stot_g[img * PIX + i0 + r * 16 + c];
    }

    const short* ajg = (const short*)AJ + ((size_t)img * PIX + jsp * JRANGE) * ROWS;

    // Hoisted staging coordinates (384 float4 per chunk, 256 threads, 2 reps).
    int row0 = tid / 12, seg0 = tid % 12;
    int row1 = (tid + 256) / 12, seg1 = (tid + 256) % 12;

    auto stage_chunk = [&](int it, int buf) {
        const short* base = ajg + (size_t)it * JCH * ROWS;
        *(float4*)(&stage[buf][row0 * LROW + seg0 * 8]) =
            *(const float4*)(base + row0 * ROWS + seg0 * 8);
        if (tid < JCH * 12 - 256) {
            *(float4*)(&stage[buf][row1 * LROW + seg1 * 8]) =
                *(const float4*)(base + row1 * ROWS + seg1 * 8);
        }
    };

    float num = 0.0f;
    float wsum[RSUB] = {0.0f, 0.0f, 0.0f, 0.0f};

    stage_chunk(0, 0);
    for (int it = 0; it < NIT; ++it) {
        int buf = it & 1;
        __syncthreads();
        if (it + 1 < NIT) stage_chunk(it + 1, buf ^ 1);
        #pragma unroll
        for (int jt = 0; jt < 2; ++jt) {
            const short* rb = &stage[buf][(jt * 16 + c) * LROW];
            s8v a1 = *(const s8v*)(rb + sg * 8);
            s8v a2 = *(const s8v*)(rb + 32 + sg * 8);
            s8v af = *(const s8v*)(rb + 64 + sg * 8);
            f4v zero = {0.0f, 0.0f, 0.0f, 0.0f};
            f4v g[RSUB], lw[RSUB];
            #pragma unroll
            for (int r = 0; r < RSUB; ++r) g[r] = __builtin_amdgcn_mfma_f32_16x16x32_bf16(a1, b1[r], zero, 0, 0, 0);
            #pragma unroll
            for (int r = 0; r < RSUB; ++r) g[r] = __builtin_amdgcn_mfma_f32_16x16x32_bf16(a2, b2[r], g[r], 0, 0, 0);
            #pragma unroll
            for (int r = 0; r < RSUB; ++r) lw[r] = __builtin_amdgcn_mfma_f32_16x16x32_bf16(af, bf[r], zero, 0, 0, 0);
            #pragma unroll
            for (int r = 0; r < RSUB; ++r) {
                #pragma unroll
                for (int qd = 0; qd < 4; ++qd) {
                    float w = fast_exp2(fminf(lw[r][qd], 0.0f));
                    num = fmaf(w, g[r][qd], num);
                    wsum[r] += w;
                }
            }
        }
    }

    float den = 0.0f;
    #pragma unroll
    for (int r = 0; r < RSUB; ++r) den = fmaf(stc[r], wsum[r], den);

    #pragma unroll
    for (int off = 32; off; off >>= 1) {
        num += __shfl_down(num, off);
        den += __shfl_down(den, off);
    }
    if (lane == 0) { red[0][wv] = num; red[1][wv] = den; }
    __syncthreads();
    if (tid == 0) {
        float a = 0.0f, d = 0.0f;
        #pragma unroll
        for (int w2 = 0; w2 < 4; ++w2) { a += red[0][w2]; d += red[1][w2]; }
        atomicAdd(&acc[0], (double)a);
        atomicAdd(&acc[1], (double)d);
    }
}

__global__ void final_kernel(const double* __restrict__ acc, float* __restrict__ out) {
    out[0] = (float)(-(acc[0] / acc[1]) / (double)NIMG);
}

extern "C" void kernel_launch(void* const* d_in, const int* in_sizes, int n_in,
                              void* d_out, int out_size, void* d_ws, size_t ws_size,
                              hipStream_t stream) {
    const float* images = (const float*)d_in[0];
    const float* segs   = (const float*)d_in[1];
    const float* rois   = (const float*)d_in[2];
    float* out = (float*)d_out;

    double* acc = (double*)d_ws;
    __hip_bfloat16* AJ = (__hip_bfloat16*)((char*)d_ws + 256);
    __hip_bfloat16* BI = AJ + (size_t)NIMG * PIX * ROWS;
    float* stot = (float*)(BI + (size_t)NIMG * PIX * ROWS);

    prep_kernel<<<NIMG * PIX / 64, 64, 0, stream>>>(images, segs, rois, AJ, BI, stot, acc);
    pair_kernel<<<NIMG * 16 * JSPLIT, 256, 0, stream>>>(AJ, BI, stot, acc);
    final_kernel<<<1, 1, 0, stream>>>(acc, out);
}

// Round 5
// 78.597 us; speedup vs baseline: 1.6252x; 1.0110x over previous
//
#include <hip/hip_runtime.h>
#include <hip/hip_bf16.h>

// NormalizedCutLoss v5: symmetric-triangle MFMA pair-tiles, no barriers.
// Per pixel two packed bf16 rows (96 bf16 = 192B):
//  A-side (j): [Shi(21)|Slo(21)|Shi(21)|0] [gh5|gl5|gh5|1|1|ph|pl|0*13]  g=log2e*f, p=log2e*(-sq/2)
//  B-side (i): [Shi(21)|Shi(21)|Slo(21)|0] [fh5|fh5|fl5|th|tl|1|1|0*13]  t=log2e*(-sq/2)
// Gram (2 MFMA over K=64) = S_j.S_i compensated; lw MFMA = log2e*(-d2/2).
// den MFMA (built in-reg from packed stot): A=[sjh,sjl,1,1], B=[1,1,sih,sil]
//   -> d_ij = stot_j + stot_i   (off-diag; covers both pair orders)
//   -> diag blocks zero the A dw0: d_ij = stot_i.
// Triangle: 120 off-diag tile-pairs (num x2) + 16 diag tiles per image.

#define NIMG 8
#define KSEG 21
#define PIX 4096
#define HI 128
#define WI 128
#define ROWS 96
#define TSZ 256          // i/j tile size (16 tiles per image)
#define NIT 8            // jt iterations per block (128 j rows = half tile)
#define LOG2E 1.4426950408889634f

typedef __attribute__((ext_vector_type(8))) short s8v;
typedef __attribute__((ext_vector_type(4))) float f4v;
typedef __attribute__((ext_vector_type(4))) int i4v;

__device__ inline s8v cast_s8v(i4v v) { union { i4v i; s8v s; } u; u.i = v; return u.s; }

__device__ inline float fast_exp2(float x) {
#if __has_builtin(__builtin_amdgcn_exp2f)
    return __builtin_amdgcn_exp2f(x);
#else
    return exp2f(x);
#endif
}

__device__ inline void hilo(float x, __hip_bfloat16& h, __hip_bfloat16& l) {
    h = __float2bfloat16(x);
    l = __float2bfloat16(x - __bfloat162float(h));
}

__global__ __launch_bounds__(256)
void prep_kernel(const float* __restrict__ images,
                 const float* __restrict__ segs,
                 const float* __restrict__ rois,
                 __hip_bfloat16* __restrict__ AJ,
                 __hip_bfloat16* __restrict__ BI,
                 unsigned* __restrict__ stotP,
                 double* __restrict__ acc) {
    __shared__ __align__(16) __hip_bfloat16 rows[256 * ROWS];
    int tid = threadIdx.x;
    int p = blockIdx.x * 256 + tid;
    if (blockIdx.x == 0 && tid == 0) { acc[0] = 0.0; acc[1] = 0.0; }

    int img = p >> 12, pp = p & 4095;
    int y = pp >> 6, x = pp & 63;
    int yi = 2 * y, xi = 2 * x;

    const float* im = images + (size_t)img * 3 * HI * WI;
    float f[5];
    f[0] = im[0 * HI * WI + yi * WI + xi] * (1.0f / 15.0f);
    f[1] = im[1 * HI * WI + yi * WI + xi] * (1.0f / 15.0f);
    f[2] = im[2 * HI * WI + yi * WI + xi] * (1.0f / 15.0f);
    f[3] = (float)x * (1.0f / 40.0f);
    f[4] = (float)y * (1.0f / 40.0f);
    float roi = rois[(size_t)img * HI * WI + yi * WI + xi];
    float sq = f[0]*f[0] + f[1]*f[1] + f[2]*f[2] + f[3]*f[3] + f[4]*f[4];

    float sv[KSEG], stot = 0.0f;
    const float* sgp = segs + (size_t)img * KSEG * HI * WI + yi * WI + xi;
    #pragma unroll
    for (int k = 0; k < KSEG; ++k) {
        const float* s2 = sgp + (size_t)k * HI * WI;
        sv[k] = 0.25f * (s2[0] + s2[1] + s2[WI] + s2[WI + 1]) * roi;
        stot += sv[k];
    }
    {
        __hip_bfloat16 sh, sl; hilo(stot, sh, sl);
        stotP[p] = (unsigned)__bfloat16_as_ushort(sh) |
                   ((unsigned)__bfloat16_as_ushort(sl) << 16);
    }
    float q = -0.5f * sq * LOG2E;
    __hip_bfloat16 one = __float2bfloat16(1.0f);
    __hip_bfloat16 zero = __float2bfloat16(0.0f);
    __hip_bfloat16 qh, ql; hilo(q, qh, ql);

    __hip_bfloat16* rp = rows + tid * ROWS;

    // ---- pass A: A-side (j) rows (f-block scaled by log2e) ----
    #pragma unroll
    for (int k = 0; k < KSEG; ++k) {
        __hip_bfloat16 h, l; hilo(sv[k], h, l);
        rp[k] = h; rp[21 + k] = l; rp[42 + k] = h;
    }
    rp[63] = zero;
    #pragma unroll
    for (int c = 0; c < 5; ++c) {
        __hip_bfloat16 h, l; hilo(f[c] * LOG2E, h, l);
        rp[64 + c] = h; rp[69 + c] = l; rp[74 + c] = h;
    }
    rp[79] = one; rp[80] = one; rp[81] = qh; rp[82] = ql;
    #pragma unroll
    for (int k = 83; k < 96; ++k) rp[k] = zero;
    __syncthreads();
    {
        const float4* rv = (const float4*)rows;
        float4* dst = (float4*)(AJ + (size_t)blockIdx.x * 256 * ROWS);
        #pragma unroll
        for (int r = 0; r < 12; ++r) dst[tid + 256 * r] = rv[tid + 256 * r];
    }
    __syncthreads();

    // ---- pass B: B-side (i) rows (f unscaled, q scaled) ----
    #pragma unroll
    for (int k = 0; k < KSEG; ++k) {
        __hip_bfloat16 h, l; hilo(sv[k], h, l);
        rp[k] = h; rp[21 + k] = h; rp[42 + k] = l;
    }
    rp[63] = zero;
    #pragma unroll
    for (int c = 0; c < 5; ++c) {
        __hip_bfloat16 h, l; hilo(f[c], h, l);
        rp[64 + c] = h; rp[69 + c] = h; rp[74 + c] = l;
    }
    rp[79] = qh; rp[80] = ql; rp[81] = one; rp[82] = one;
    #pragma unroll
    for (int k = 83; k < 96; ++k) rp[k] = zero;
    __syncthreads();
    {
        const float4* rv = (const float4*)rows;
        float4* dst = (float4*)(BI + (size_t)blockIdx.x * 256 * ROWS);
        #pragma unroll
        for (int r = 0; r < 12; ++r) dst[tid + 256 * r] = rv[tid + 256 * r];
    }
}

__global__ __launch_bounds__(256, 3)
void pair_kernel(const short* __restrict__ AJ,
                 const short* __restrict__ BI,
                 const unsigned* __restrict__ stotP,
                 double* __restrict__ acc) {
    __shared__ float red[2][4];

    int tid = threadIdx.x, lane = tid & 63, wv = tid >> 6;
    int c = lane & 15, sg = lane >> 4;
    int bid = blockIdx.x;
    int img = bid & 7;                 // XCD-affine: one image per XCD
    int rest = bid >> 3;               // [0, 272)
    int tp = rest >> 1, jh = rest & 1;
    int I, J; bool diag;
    if (tp >= 120) { I = J = tp - 120; diag = true; }
    else {
        diag = false;
        int t = tp; I = 0;
        while (t >= 15 - I) { t -= 15 - I; ++I; }
        J = I + 1 + t;
    }
    size_t ibase = (size_t)img * PIX + I * TSZ;
    size_t jbase = (size_t)img * PIX + J * TSZ + jh * 128;
    int i0 = wv * 64;

    unsigned lead1 = (sg == 0) ? 0x3F803F80u : 0u;          // [1,1] bf16 pair
    unsigned admask = (sg == 0 && !diag) ? 0xFFFFFFFFu : 0u;

    // B-side fragments, held in registers for the whole j-loop.
    s8v b1[4], b2[4], bf[4], bd[4];
    #pragma unroll
    for (int r = 0; r < 4; ++r) {
        const short* bp = BI + (ibase + i0 + r * 16 + c) * ROWS;
        b1[r] = *(const s8v*)(bp + sg * 8);
        b2[r] = *(const s8v*)(bp + 32 + sg * 8);
        bf[r] = *(const s8v*)(bp + 64 + sg * 8);
        unsigned sp = stotP[ibase + i0 + r * 16 + c];
        i4v bdi = { (int)lead1, (int)((sg == 0) ? sp : 0u), 0, 0 };
        bd[r] = cast_s8v(bdi);
    }

    const short* arow = AJ + (jbase + c) * ROWS;
    const unsigned* spJ = stotP + jbase + c;

    float num[4] = {0,0,0,0}, den[4] = {0,0,0,0};

    // 1-deep register prefetch, no LDS, no barriers.
    s8v a1c = *(const s8v*)(arow + sg * 8);
    s8v a2c = *(const s8v*)(arow + 32 + sg * 8);
    s8v afc = *(const s8v*)(arow + 64 + sg * 8);
    unsigned d0c = spJ[0];

    #pragma unroll 4
    for (int jt = 0; jt < NIT; ++jt) {
        int nj = (jt + 1) & (NIT - 1);
        const short* ap = arow + nj * (16 * ROWS);
        s8v a1n = *(const s8v*)(ap + sg * 8);
        s8v a2n = *(const s8v*)(ap + 32 + sg * 8);
        s8v afn = *(const s8v*)(ap + 64 + sg * 8);
        unsigned d0n = spJ[nj * 16];

        i4v adi = { (int)(d0c & admask), (int)lead1, 0, 0 };
        s8v ad = cast_s8v(adi);

        f4v z = {0,0,0,0};
        f4v g[4], lw[4], sd[4];
        #pragma unroll
        for (int r = 0; r < 4; ++r) g[r] = __builtin_amdgcn_mfma_f32_16x16x32_bf16(a1c, b1[r], z, 0, 0, 0);
        #pragma unroll
        for (int r = 0; r < 4; ++r) g[r] = __builtin_amdgcn_mfma_f32_16x16x32_bf16(a2c, b2[r], g[r], 0, 0, 0);
        #pragma unroll
        for (int r = 0; r < 4; ++r) lw[r] = __builtin_amdgcn_mfma_f32_16x16x32_bf16(afc, bf[r], z, 0, 0, 0);
        #pragma unroll
        for (int r = 0; r < 4; ++r) sd[r] = __builtin_amdgcn_mfma_f32_16x16x32_bf16(ad, bd[r], z, 0, 0, 0);

        #pragma unroll
        for (int r = 0; r < 4; ++r) {
            #pragma unroll
            for (int qd = 0; qd < 4; ++qd) {
                float w = fast_exp2(lw[r][qd]);
                num[r] = fmaf(w, g[r][qd], num[r]);
                den[r] = fmaf(w, sd[r][qd], den[r]);
            }
        }
        a1c = a1n; a2c = a2n; afc = afn; d0c = d0n;
    }

    float numt = (num[0] + num[1]) + (num[2] + num[3]);
    float dent = (den[0] + den[1]) + (den[2] + den[3]);
    if (!diag) numt *= 2.0f;           // off-diag tiles: both pair orders

    #pragma unroll
    for (int off = 32; off; off >>= 1) {
        numt += __shfl_down(numt, off);
        dent += __shfl_down(dent, off);
    }
    if (lane == 0) { red[0][wv] = numt; red[1][wv] = dent; }
    __syncthreads();
    if (tid == 0) {
        float a = 0.0f, d = 0.0f;
        #pragma unroll
        for (int w2 = 0; w2 < 4; ++w2) { a += red[0][w2]; d += red[1][w2]; }
        atomicAdd(&acc[0], (double)a);
        atomicAdd(&acc[1], (double)d);
    }
}

__global__ void final_kernel(const double* __restrict__ acc, float* __restrict__ out) {
    out[0] = (float)(-(acc[0] / acc[1]) / (double)NIMG);
}

extern "C" void kernel_launch(void* const* d_in, const int* in_sizes, int n_in,
                              void* d_out, int out_size, void* d_ws, size_t ws_size,
                              hipStream_t stream) {
    const float* images = (const float*)d_in[0];
    const float* segs   = (const float*)d_in[1];
    const float* rois   = (const float*)d_in[2];
    float* out = (float*)d_out;

    double* acc = (double*)d_ws;
    __hip_bfloat16* AJ = (__hip_bfloat16*)((char*)d_ws + 256);
    __hip_bfloat16* BI = AJ + (size_t)NIMG * PIX * ROWS;
    unsigned* stotP = (unsigned*)(BI + (size_t)NIMG * PIX * ROWS);

    prep_kernel<<<NIMG * PIX / 256, 256, 0, stream>>>(images, segs, rois, AJ, BI, stotP, acc);
    pair_kernel<<<NIMG * 272, 256, 0, stream>>>((const short*)AJ, (const short*)BI, stotP, acc);
    final_kernel<<<1, 1, 0, stream>>>(acc, out);
}

// Round 6
// 46.530 us; speedup vs baseline: 2.7452x; 1.6892x over previous
//
#include <hip/hip_runtime.h>
#include <hip/hip_bf16.h>

// NormalizedCutLoss v6: symmetric-triangle MFMA pair-tiles, no barriers,
// NO global atomics (per-block partials + separate reduction kernel).
// Per pixel two packed bf16 rows (96 bf16 = 192B):
//  A-side (j): [Shi(21)|Slo(21)|Shi(21)|0] [gh5|gl5|gh5|1|1|ph|pl|0*13]  g=log2e*f, p=log2e*(-sq/2)
//  B-side (i): [Shi(21)|Shi(21)|Slo(21)|0] [fh5|fh5|fl5|th|tl|1|1|0*13]  t=log2e*(-sq/2)
// Gram (2 MFMA over K=64) = S_j.S_i compensated; lw MFMA = log2e*(-d2/2).
// den MFMA: A=[sjh,sjl,1,1](masked on diag), B=[1,1,sih,sil] -> stot_j+stot_i.
// Triangle: 120 off-diag tile-pairs (num x2) + 16 diag tiles per image.

#define NIMG 8
#define KSEG 21
#define PIX 4096
#define HI 128
#define WI 128
#define ROWS 96
#define TSZ 256
#define NIT 8
#define NBLK (NIMG * 272)       // 2176 pair blocks
#define LOG2E 1.4426950408889634f

typedef __attribute__((ext_vector_type(8))) short s8v;
typedef __attribute__((ext_vector_type(4))) float f4v;
typedef __attribute__((ext_vector_type(4))) int i4v;

__device__ inline s8v cast_s8v(i4v v) { union { i4v i; s8v s; } u; u.i = v; return u.s; }

__device__ inline float fast_exp2(float x) {
#if __has_builtin(__builtin_amdgcn_exp2f)
    return __builtin_amdgcn_exp2f(x);
#else
    return exp2f(x);
#endif
}

__device__ inline void hilo(float x, __hip_bfloat16& h, __hip_bfloat16& l) {
    h = __float2bfloat16(x);
    l = __float2bfloat16(x - __bfloat162float(h));
}

__global__ __launch_bounds__(256)
void prep_kernel(const float* __restrict__ images,
                 const float* __restrict__ segs,
                 const float* __restrict__ rois,
                 __hip_bfloat16* __restrict__ AJ,
                 __hip_bfloat16* __restrict__ BI,
                 unsigned* __restrict__ stotP) {
    __shared__ __align__(16) __hip_bfloat16 rows[256 * ROWS];
    int tid = threadIdx.x;
    int p = blockIdx.x * 256 + tid;

    int img = p >> 12, pp = p & 4095;
    int y = pp >> 6, x = pp & 63;
    int yi = 2 * y, xi = 2 * x;

    const float* im = images + (size_t)img * 3 * HI * WI;
    float f[5];
    f[0] = im[0 * HI * WI + yi * WI + xi] * (1.0f / 15.0f);
    f[1] = im[1 * HI * WI + yi * WI + xi] * (1.0f / 15.0f);
    f[2] = im[2 * HI * WI + yi * WI + xi] * (1.0f / 15.0f);
    f[3] = (float)x * (1.0f / 40.0f);
    f[4] = (float)y * (1.0f / 40.0f);
    float roi = rois[(size_t)img * HI * WI + yi * WI + xi];
    float sq = f[0]*f[0] + f[1]*f[1] + f[2]*f[2] + f[3]*f[3] + f[4]*f[4];

    float sv[KSEG], stot = 0.0f;
    const float2* sgp2 = (const float2*)(segs + (size_t)img * KSEG * HI * WI + yi * WI + xi);
    #pragma unroll
    for (int k = 0; k < KSEG; ++k) {
        float2 t = sgp2[k * (HI * WI / 2)];
        float2 u = sgp2[k * (HI * WI / 2) + WI / 2];
        sv[k] = 0.25f * ((t.x + t.y) + (u.x + u.y)) * roi;
        stot += sv[k];
    }
    {
        __hip_bfloat16 sh, sl; hilo(stot, sh, sl);
        stotP[p] = (unsigned)__bfloat16_as_ushort(sh) |
                   ((unsigned)__bfloat16_as_ushort(sl) << 16);
    }
    float q = -0.5f * sq * LOG2E;
    __hip_bfloat16 one = __float2bfloat16(1.0f);
    __hip_bfloat16 zero = __float2bfloat16(0.0f);
    __hip_bfloat16 qh, ql; hilo(q, qh, ql);

    __hip_bfloat16* rp = rows + tid * ROWS;

    // ---- pass A: A-side (j) rows (f-block scaled by log2e) ----
    #pragma unroll
    for (int k = 0; k < KSEG; ++k) {
        __hip_bfloat16 h, l; hilo(sv[k], h, l);
        rp[k] = h; rp[21 + k] = l; rp[42 + k] = h;
    }
    rp[63] = zero;
    #pragma unroll
    for (int c = 0; c < 5; ++c) {
        __hip_bfloat16 h, l; hilo(f[c] * LOG2E, h, l);
        rp[64 + c] = h; rp[69 + c] = l; rp[74 + c] = h;
    }
    rp[79] = one; rp[80] = one; rp[81] = qh; rp[82] = ql;
    #pragma unroll
    for (int k = 83; k < 96; ++k) rp[k] = zero;
    __syncthreads();
    {
        const float4* rv = (const float4*)rows;
        float4* dst = (float4*)(AJ + (size_t)blockIdx.x * 256 * ROWS);
        #pragma unroll
        for (int r = 0; r < 12; ++r) dst[tid + 256 * r] = rv[tid + 256 * r];
    }
    __syncthreads();

    // ---- pass B: B-side (i) rows (f unscaled, q scaled) ----
    #pragma unroll
    for (int k = 0; k < KSEG; ++k) {
        __hip_bfloat16 h, l; hilo(sv[k], h, l);
        rp[k] = h; rp[21 + k] = h; rp[42 + k] = l;
    }
    rp[63] = zero;
    #pragma unroll
    for (int c = 0; c < 5; ++c) {
        __hip_bfloat16 h, l; hilo(f[c], h, l);
        rp[64 + c] = h; rp[69 + c] = h; rp[74 + c] = l;
    }
    rp[79] = qh; rp[80] = ql; rp[81] = one; rp[82] = one;
    #pragma unroll
    for (int k = 83; k < 96; ++k) rp[k] = zero;
    __syncthreads();
    {
        const float4* rv = (const float4*)rows;
        float4* dst = (float4*)(BI + (size_t)blockIdx.x * 256 * ROWS);
        #pragma unroll
        for (int r = 0; r < 12; ++r) dst[tid + 256 * r] = rv[tid + 256 * r];
    }
}

__global__ __launch_bounds__(256, 3)
void pair_kernel(const short* __restrict__ AJ,
                 const short* __restrict__ BI,
                 const unsigned* __restrict__ stotP,
                 float2* __restrict__ partials) {
    __shared__ float red[2][4];

    int tid = threadIdx.x, lane = tid & 63, wv = tid >> 6;
    int c = lane & 15, sg = lane >> 4;
    int bid = blockIdx.x;
    int img = bid & 7;                 // XCD-affine: one image per XCD
    int rest = bid >> 3;               // [0, 272)
    int tp = rest >> 1, jh = rest & 1;
    int I, J; bool diag;
    if (tp >= 120) { I = J = tp - 120; diag = true; }
    else {
        diag = false;
        int t = tp; I = 0;
        while (t >= 15 - I) { t -= 15 - I; ++I; }
        J = I + 1 + t;
    }
    size_t ibase = (size_t)img * PIX + I * TSZ;
    size_t jbase = (size_t)img * PIX + J * TSZ + jh * 128;
    int i0 = wv * 64;

    unsigned lead1 = (sg == 0) ? 0x3F803F80u : 0u;          // [1,1] bf16 pair
    unsigned admask = (sg == 0 && !diag) ? 0xFFFFFFFFu : 0u;

    // B-side fragments, held in registers for the whole j-loop.
    s8v b1[4], b2[4], bf[4], bd[4];
    #pragma unroll
    for (int r = 0; r < 4; ++r) {
        const short* bp = BI + (ibase + i0 + r * 16 + c) * ROWS;
        b1[r] = *(const s8v*)(bp + sg * 8);
        b2[r] = *(const s8v*)(bp + 32 + sg * 8);
        bf[r] = *(const s8v*)(bp + 64 + sg * 8);
        unsigned sp = stotP[ibase + i0 + r * 16 + c];
        i4v bdi = { (int)lead1, (int)((sg == 0) ? sp : 0u), 0, 0 };
        bd[r] = cast_s8v(bdi);
    }

    const short* arow = AJ + (jbase + c) * ROWS;
    const unsigned* spJ = stotP + jbase + c;

    float num[4] = {0,0,0,0}, den[4] = {0,0,0,0};

    // 1-deep register prefetch, no LDS, no barriers.
    s8v a1c = *(const s8v*)(arow + sg * 8);
    s8v a2c = *(const s8v*)(arow + 32 + sg * 8);
    s8v afc = *(const s8v*)(arow + 64 + sg * 8);
    unsigned d0c = spJ[0];

    #pragma unroll 4
    for (int jt = 0; jt < NIT; ++jt) {
        int nj = (jt + 1) & (NIT - 1);
        const short* ap = arow + nj * (16 * ROWS);
        s8v a1n = *(const s8v*)(ap + sg * 8);
        s8v a2n = *(const s8v*)(ap + 32 + sg * 8);
        s8v afn = *(const s8v*)(ap + 64 + sg * 8);
        unsigned d0n = spJ[nj * 16];

        i4v adi = { (int)(d0c & admask), (int)lead1, 0, 0 };
        s8v ad = cast_s8v(adi);

        f4v z = {0,0,0,0};
        f4v g[4], lw[4], sd[4];
        #pragma unroll
        for (int r = 0; r < 4; ++r) g[r] = __builtin_amdgcn_mfma_f32_16x16x32_bf16(a1c, b1[r], z, 0, 0, 0);
        #pragma unroll
        for (int r = 0; r < 4; ++r) g[r] = __builtin_amdgcn_mfma_f32_16x16x32_bf16(a2c, b2[r], g[r], 0, 0, 0);
        #pragma unroll
        for (int r = 0; r < 4; ++r) lw[r] = __builtin_amdgcn_mfma_f32_16x16x32_bf16(afc, bf[r], z, 0, 0, 0);
        #pragma unroll
        for (int r = 0; r < 4; ++r) sd[r] = __builtin_amdgcn_mfma_f32_16x16x32_bf16(ad, bd[r], z, 0, 0, 0);

        #pragma unroll
        for (int r = 0; r < 4; ++r) {
            #pragma unroll
            for (int qd = 0; qd < 4; ++qd) {
                float w = fast_exp2(lw[r][qd]);
                num[r] = fmaf(w, g[r][qd], num[r]);
                den[r] = fmaf(w, sd[r][qd], den[r]);
            }
        }
        a1c = a1n; a2c = a2n; afc = afn; d0c = d0n;
    }

    float numt = (num[0] + num[1]) + (num[2] + num[3]);
    float dent = (den[0] + den[1]) + (den[2] + den[3]);
    if (!diag) numt *= 2.0f;           // off-diag tiles: both pair orders

    #pragma unroll
    for (int off = 32; off; off >>= 1) {
        numt += __shfl_down(numt, off);
        dent += __shfl_down(dent, off);
    }
    if (lane == 0) { red[0][wv] = numt; red[1][wv] = dent; }
    __syncthreads();
    if (tid == 0) {
        float a = (red[0][0] + red[0][1]) + (red[0][2] + red[0][3]);
        float d = (red[1][0] + red[1][1]) + (red[1][2] + red[1][3]);
        partials[bid] = make_float2(a, d);   // private slot: NO atomics
    }
}

__global__ __launch_bounds__(256)
void final_kernel(const float2* __restrict__ partials, float* __restrict__ out) {
    __shared__ double sa[4], sd_[4];
    int tid = threadIdx.x, lane = tid & 63, wv = tid >> 6;
    double a = 0.0, d = 0.0;
    for (int i = tid; i < NBLK; i += 256) {
        float2 p = partials[i];
        a += (double)p.x; d += (double)p.y;
    }
    #pragma unroll
    for (int off = 32; off; off >>= 1) {
        a += __shfl_down(a, off);
        d += __shfl_down(d, off);
    }
    if (lane == 0) { sa[wv] = a; sd_[wv] = d; }
    __syncthreads();
    if (tid == 0) {
        double A = (sa[0] + sa[1]) + (sa[2] + sa[3]);
        double D = (sd_[0] + sd_[1]) + (sd_[2] + sd_[3]);
        out[0] = (float)(-(A / D) / (double)NIMG);
    }
}

extern "C" void kernel_launch(void* const* d_in, const int* in_sizes, int n_in,
                              void* d_out, int out_size, void* d_ws, size_t ws_size,
                              hipStream_t stream) {
    const float* images = (const float*)d_in[0];
    const float* segs   = (const float*)d_in[1];
    const float* rois   = (const float*)d_in[2];
    float* out = (float*)d_out;

    float2* partials = (float2*)d_ws;                              // 2176 * 8B
    __hip_bfloat16* AJ = (__hip_bfloat16*)((char*)d_ws + 32768);
    __hip_bfloat16* BI = AJ + (size_t)NIMG * PIX * ROWS;
    unsigned* stotP = (unsigned*)(BI + (size_t)NIMG * PIX * ROWS);

    prep_kernel<<<NIMG * PIX / 256, 256, 0, stream>>>(images, segs, rois, AJ, BI, stotP);
    pair_kernel<<<NBLK, 256, 0, stream>>>((const short*)AJ, (const short*)BI, stotP, partials);
    final_kernel<<<1, 256, 0, stream>>>(partials, out);
}

// Round 7
// 43.200 us; speedup vs baseline: 2.9568x; 1.0771x over previous
//
#include <hip/hip_runtime.h>
#include <hip/hip_bf16.h>

// NormalizedCutLoss v7: symmetric triangle of 256x256 tile-pairs.
// A staged once per block via double-buffered LDS (shared by 4 waves),
// B-fragments in registers (64 i/wave), no atomics, stot_j via float4 load.
// Per pixel two packed bf16 rows (96 bf16 = 192B):
//  A-side (j): [Shi21|Slo21|Shi21|0][gh5|gl5|gh5|1|1|ph|pl|0*13]  g=log2e*f, p=log2e*(-sq/2)
//  B-side (i): [Shi21|Shi21|Slo21|0][fh5|fh5|fl5|th|tl|1|1|0*13]  t=log2e*(-sq/2)
// per 16x16 tile: 2 MFMA -> Gram (compensated), 1 MFMA -> log2e*(-d2/2).
// w = exp2(lw); num += w*Gram; den += w*(stot_i + stot_j)  (stot_j=0 on diag).
// Triangle: 120 off-diag pairs (num x2) + 16 diag tiles per image.

#define NIMG 8
#define KSEG 21
#define PIX 4096
#define HI 128
#define WI 128
#define ROWS 96
#define LROW 104           // LDS row stride in shorts (208B)
#define TSZ 256
#define JCH 32             // A-rows per staged chunk
#define NCH (TSZ / JCH)    // 8
#define NBLK (NIMG * 136)  // 1088
#define LOG2E 1.4426950408889634f

typedef __attribute__((ext_vector_type(8))) short s8v;
typedef __attribute__((ext_vector_type(4))) float f4v;

__device__ inline float fast_exp2(float x) {
#if __has_builtin(__builtin_amdgcn_exp2f)
    return __builtin_amdgcn_exp2f(x);
#else
    return exp2f(x);
#endif
}

__device__ inline void hilo_us(float x, unsigned short& h, unsigned short& l) {
    __hip_bfloat16 hb = __float2bfloat16(x);
    __hip_bfloat16 lb = __float2bfloat16(x - __bfloat162float(hb));
    h = __bfloat16_as_ushort(hb);
    l = __bfloat16_as_ushort(lb);
}

#define BF1 ((unsigned short)0x3F80)   // 1.0 bf16

__global__ __launch_bounds__(128)
void prep_kernel(const float* __restrict__ images,
                 const float* __restrict__ segs,
                 const float* __restrict__ rois,
                 short* __restrict__ AJ,
                 short* __restrict__ BI,
                 float* __restrict__ stotF) {
    int tid = threadIdx.x;
    int p = blockIdx.x * 128 + tid;
    int img = p >> 12, pp = p & 4095;
    int y = pp >> 6, x = pp & 63;
    int yi = 2 * y, xi = 2 * x;

    const float* im = images + (size_t)img * 3 * HI * WI;
    float f[5];
    f[0] = im[0 * HI * WI + yi * WI + xi] * (1.0f / 15.0f);
    f[1] = im[1 * HI * WI + yi * WI + xi] * (1.0f / 15.0f);
    f[2] = im[2 * HI * WI + yi * WI + xi] * (1.0f / 15.0f);
    f[3] = (float)x * (1.0f / 40.0f);
    f[4] = (float)y * (1.0f / 40.0f);
    float roi = rois[(size_t)img * HI * WI + yi * WI + xi];
    float sq = f[0]*f[0] + f[1]*f[1] + f[2]*f[2] + f[3]*f[3] + f[4]*f[4];

    float sv[KSEG], stot = 0.0f;
    const float2* sgp2 = (const float2*)(segs + (size_t)img * KSEG * HI * WI + yi * WI + xi);
    #pragma unroll
    for (int k = 0; k < KSEG; ++k) {
        float2 t = sgp2[k * (HI * WI / 2)];
        float2 u = sgp2[k * (HI * WI / 2) + WI / 2];
        sv[k] = 0.25f * ((t.x + t.y) + (u.x + u.y)) * roi;
        stot += sv[k];
    }
    stotF[p] = stot;
    float q = -0.5f * sq * LOG2E;
    unsigned short qh, ql; hilo_us(q, qh, ql);

    unsigned short sh[KSEG], sl[KSEG], fh[5], fl[5], gh[5], gl[5];
    #pragma unroll
    for (int k = 0; k < KSEG; ++k) hilo_us(sv[k], sh[k], sl[k]);
    #pragma unroll
    for (int c = 0; c < 5; ++c) { hilo_us(f[c], fh[c], fl[c]); hilo_us(f[c] * LOG2E, gh[c], gl[c]); }

    unsigned short e[ROWS];

    // ---- A-side (j): [Sh|Sl|Sh|0][gh|gl|gh|1|1|qh|ql|0..] ----
    #pragma unroll
    for (int k = 0; k < KSEG; ++k) { e[k] = sh[k]; e[21 + k] = sl[k]; e[42 + k] = sh[k]; }
    e[63] = 0;
    #pragma unroll
    for (int c = 0; c < 5; ++c) { e[64 + c] = gh[c]; e[69 + c] = gl[c]; e[74 + c] = gh[c]; }
    e[79] = BF1; e[80] = BF1; e[81] = qh; e[82] = ql;
    #pragma unroll
    for (int k = 83; k < ROWS; ++k) e[k] = 0;
    {
        short* dst = AJ + (size_t)p * ROWS;
        #pragma unroll
        for (int qd = 0; qd < 12; ++qd) {
            int4 v;
            v.x = (unsigned)e[qd*8+0] | ((unsigned)e[qd*8+1] << 16);
            v.y = (unsigned)e[qd*8+2] | ((unsigned)e[qd*8+3] << 16);
            v.z = (unsigned)e[qd*8+4] | ((unsigned)e[qd*8+5] << 16);
            v.w = (unsigned)e[qd*8+6] | ((unsigned)e[qd*8+7] << 16);
            *(int4*)(dst + qd * 8) = v;
        }
    }

    // ---- B-side (i): [Sh|Sh|Sl|0][fh|fh|fl|qh|ql|1|1|0..] ----
    #pragma unroll
    for (int k = 0; k < KSEG; ++k) { e[k] = sh[k]; e[21 + k] = sh[k]; e[42 + k] = sl[k]; }
    e[63] = 0;
    #pragma unroll
    for (int c = 0; c < 5; ++c) { e[64 + c] = fh[c]; e[69 + c] = fh[c]; e[74 + c] = fl[c]; }
    e[79] = qh; e[80] = ql; e[81] = BF1; e[82] = BF1;
    #pragma unroll
    for (int k = 83; k < ROWS; ++k) e[k] = 0;
    {
        short* dst = BI + (size_t)p * ROWS;
        #pragma unroll
        for (int qd = 0; qd < 12; ++qd) {
            int4 v;
            v.x = (unsigned)e[qd*8+0] | ((unsigned)e[qd*8+1] << 16);
            v.y = (unsigned)e[qd*8+2] | ((unsigned)e[qd*8+3] << 16);
            v.z = (unsigned)e[qd*8+4] | ((unsigned)e[qd*8+5] << 16);
            v.w = (unsigned)e[qd*8+6] | ((unsigned)e[qd*8+7] << 16);
            *(int4*)(dst + qd * 8) = v;
        }
    }
}

__global__ __launch_bounds__(256, 3)
void pair_kernel(const short* __restrict__ AJ,
                 const short* __restrict__ BI,
                 const float* __restrict__ stotF,
                 float2* __restrict__ partials) {
    __shared__ __align__(16) short stage[2][JCH * LROW];   // 2 * 6656B
    __shared__ float red[2][4];

    int tid = threadIdx.x, lane = tid & 63, wv = tid >> 6;
    int c = lane & 15, sg = lane >> 4;
    int bid = blockIdx.x;
    int img = bid & 7;                 // XCD-affine: one image per XCD
    int tp = bid >> 3;                 // [0, 136)
    int I, J; bool diag;
    if (tp >= 120) { I = J = tp - 120; diag = true; }
    else {
        diag = false;
        int t = tp; I = 0;
        while (t >= 15 - I) { t -= 15 - I; ++I; }
        J = I + 1 + t;
    }
    size_t ibase = (size_t)img * PIX + I * TSZ;
    size_t jbase = (size_t)img * PIX + J * TSZ;
    int i0 = wv * 64;

    // B-side fragments: 4 subtiles of 16 i-pixels, registers for whole j-loop.
    s8v b1[4], b2[4], bf[4];
    float stc[4];
    #pragma unroll
    for (int r = 0; r < 4; ++r) {
        const short* bp = BI + (ibase + i0 + r * 16 + c) * ROWS;
        b1[r] = *(const s8v*)(bp + sg * 8);
        b2[r] = *(const s8v*)(bp + 32 + sg * 8);
        bf[r] = *(const s8v*)(bp + 64 + sg * 8);
        stc[r] = stotF[ibase + i0 + r * 16 + c];
    }

    const short* ajg = AJ + jbase * ROWS;
    const float* stjb = stotF + jbase;

    // Staging: 32 rows * 12 float4 = 384 chunks, 256 threads (2nd rep: 128).
    int row0 = tid / 12, seg0 = tid % 12;
    int row1 = (tid + 256) / 12, seg1 = (tid + 256) % 12;
    auto stage_chunk = [&](int ch, int buf) {
        const short* base = ajg + (size_t)ch * JCH * ROWS;
        *(float4*)(&stage[buf][row0 * LROW + seg0 * 8]) =
            *(const float4*)(base + row0 * ROWS + seg0 * 8);
        if (tid < JCH * 12 - 256) {
            *(float4*)(&stage[buf][row1 * LROW + seg1 * 8]) =
                *(const float4*)(base + row1 * ROWS + seg1 * 8);
        }
    };

    float num[4] = {0,0,0,0}, den[4] = {0,0,0,0};

    stage_chunk(0, 0);
    for (int ch = 0; ch < NCH; ++ch) {
        int buf = ch & 1;
        __syncthreads();
        if (ch + 1 < NCH) stage_chunk(ch + 1, buf ^ 1);
        #pragma unroll
        for (int jtl = 0; jtl < 2; ++jtl) {
            int jt = ch * 2 + jtl;
            f4v stj = {0.0f, 0.0f, 0.0f, 0.0f};
            if (!diag) stj = *(const f4v*)(stjb + jt * 16 + sg * 4);

            const short* rb = &stage[buf][(jtl * 16 + c) * LROW];
            s8v a1 = *(const s8v*)(rb + sg * 8);
            s8v a2 = *(const s8v*)(rb + 32 + sg * 8);
            s8v af = *(const s8v*)(rb + 64 + sg * 8);

            f4v z = {0,0,0,0};
            f4v g[4], lw[4];
            #pragma unroll
            for (int r = 0; r < 4; ++r) g[r] = __builtin_amdgcn_mfma_f32_16x16x32_bf16(a1, b1[r], z, 0, 0, 0);
            #pragma unroll
            for (int r = 0; r < 4; ++r) g[r] = __builtin_amdgcn_mfma_f32_16x16x32_bf16(a2, b2[r], g[r], 0, 0, 0);
            #pragma unroll
            for (int r = 0; r < 4; ++r) lw[r] = __builtin_amdgcn_mfma_f32_16x16x32_bf16(af, bf[r], z, 0, 0, 0);

            #pragma unroll
            for (int r = 0; r < 4; ++r) {
                #pragma unroll
                for (int qd = 0; qd < 4; ++qd) {
                    float w = fast_exp2(lw[r][qd]);
                    num[r] = fmaf(w, g[r][qd], num[r]);
                    den[r] = fmaf(w, stc[r] + stj[qd], den[r]);
                }
            }
        }
    }

    float numt = (num[0] + num[1]) + (num[2] + num[3]);
    float dent = (den[0] + den[1]) + (den[2] + den[3]);
    if (!diag) numt *= 2.0f;           // off-diag tiles: both pair orders

    #pragma unroll
    for (int off = 32; off; off >>= 1) {
        numt += __shfl_down(numt, off);
        dent += __shfl_down(dent, off);
    }
    if (lane == 0) { red[0][wv] = numt; red[1][wv] = dent; }
    __syncthreads();
    if (tid == 0) {
        float a = (red[0][0] + red[0][1]) + (red[0][2] + red[0][3]);
        float d = (red[1][0] + red[1][1]) + (red[1][2] + red[1][3]);
        partials[bid] = make_float2(a, d);   // private slot: no atomics
    }
}

__global__ __launch_bounds__(256)
void final_kernel(const float2* __restrict__ partials, float* __restrict__ out) {
    __shared__ double sa[4], sd_[4];
    int tid = threadIdx.x, lane = tid & 63, wv = tid >> 6;
    double a = 0.0, d = 0.0;
    for (int i = tid; i < NBLK; i += 256) {
        float2 p = partials[i];
        a += (double)p.x; d += (double)p.y;
    }
    #pragma unroll
    for (int off = 32; off; off >>= 1) {
        a += __shfl_down(a, off);
        d += __shfl_down(d, off);
    }
    if (lane == 0) { sa[wv] = a; sd_[wv] = d; }
    __syncthreads();
    if (tid == 0) {
        double A = (sa[0] + sa[1]) + (sa[2] + sa[3]);
        double D = (sd_[0] + sd_[1]) + (sd_[2] + sd_[3]);
        out[0] = (float)(-(A / D) / (double)NIMG);
    }
}

extern "C" void kernel_launch(void* const* d_in, const int* in_sizes, int n_in,
                              void* d_out, int out_size, void* d_ws, size_t ws_size,
                              hipStream_t stream) {
    const float* images = (const float*)d_in[0];
    const float* segs   = (const float*)d_in[1];
    const float* rois   = (const float*)d_in[2];
    float* out = (float*)d_out;

    float2* partials = (float2*)d_ws;                              // 1088 * 8B
    short* AJ = (short*)((char*)d_ws + 32768);
    short* BI = AJ + (size_t)NIMG * PIX * ROWS;
    float* stotF = (float*)(BI + (size_t)NIMG * PIX * ROWS);

    prep_kernel<<<NIMG * PIX / 128, 128, 0, stream>>>(images, segs, rois, AJ, BI, stotF);
    pair_kernel<<<NBLK, 256, 0, stream>>>(AJ, BI, stotF, partials);
    final_kernel<<<1, 256, 0, stream>>>(partials, out);
}